// Round 5
// baseline (95.229 us; speedup 1.0000x reference)
//
#include <hip/hip_runtime.h>
#include <hip/hip_bf16.h>

typedef unsigned short u16;
typedef unsigned int u32;
typedef __bf16 bf16x8_t __attribute__((ext_vector_type(8)));
typedef float f32x4_t __attribute__((ext_vector_type(4)));

constexpr int Bb = 4;
constexpr int Tt = 4096;
constexpr int Dd = 64;
constexpr float QSCALE = 0.18033688011112042f; // 0.125 * log2(e), folded into q

__device__ __forceinline__ u16 f2bf(float f) { // RNE
  unsigned int u = __builtin_bit_cast(unsigned int, f);
  return (u16)((u + 0x7fffu + ((u >> 16) & 1u)) >> 16);
}
__device__ __forceinline__ u32 pk2(float a, float b) { // RNE pack
  return (u32)f2bf(a) | ((u32)f2bf(b) << 16);
}
__device__ __forceinline__ bf16x8_t ld16(const u16* p) {
  int4 v = *(const int4*)p;
  return __builtin_bit_cast(bf16x8_t, v);
}
__device__ __forceinline__ f32x4_t mfma16(bf16x8_t a, bf16x8_t b, f32x4_t c) {
  return __builtin_amdgcn_mfma_f32_16x16x32_bf16(a, b, c, 0, 0, 0);
}

// ---------------- proj v4 (R17, verified): LDS-staged x and W, fragment-order outputs ----------------
//   qS/kS tile (b*64+t): frag(idx,kk) @ (idx*2+kk)*512 + lane*8 u16
//   vS  tile (b*64+kt):  frag(kk,dt)  @ (kk*4+dt)*512 + lane*8 u16
__global__ __launch_bounds__(256) void HeadV1_proj(
    const float* __restrict__ x, const float* __restrict__ Wk,
    const float* __restrict__ Wq, const float* __restrict__ Wv,
    u16* __restrict__ qS, u16* __restrict__ kS, u16* __restrict__ vS)
{
  __shared__ u16 xl[64][72];      // 9216 B
  __shared__ u16 Wl[3][64][72];   // 27648 B
  __shared__ u16 ylds[64][72];    // 9216 B  (total 46 KB)

  const int t = threadIdx.x;
  const int w = t >> 6, lane = t & 63, l15 = lane & 15, quad = lane >> 4;
  const int r0 = blockIdx.x * 64;
  const int b  = r0 >> 12;
  const int kt = (r0 & 4095) >> 6;
  const long tilebase = ((long)(b * 64 + kt)) * 4096;

  { // coalesced fp32 staging with one-time bf16 conversion
    const float* srcs[4] = {x + (long)r0 * 64, Wk, Wq, Wv};
    u16* dstl[4] = {&xl[0][0], &Wl[0][0][0], &Wl[1][0][0], &Wl[2][0][0]};
    #pragma unroll
    for (int mm = 0; mm < 4; mm++) {
      const float* s = srcs[mm];
      u16* d = dstl[mm];
      #pragma unroll
      for (int i = 0; i < 4; i++) {
        const int f4 = i * 256 + t;        // 1024 float4 per 64x64 tile
        const int row = f4 >> 4, c4 = f4 & 15;
        float4 v = ((const float4*)(s + row * 64))[c4];
        uint2 pk;
        pk.x = pk2(v.x, v.y);
        pk.y = pk2(v.z, v.w);
        *(uint2*)(d + row * 72 + c4 * 4) = pk;
      }
    }
  }
  __syncthreads();

  bf16x8_t xf[2];
  #pragma unroll
  for (int kh = 0; kh < 2; kh++)
    xf[kh] = ld16(&xl[w * 16 + l15][kh * 32 + quad * 8]);

  u16* dsts[3];
  dsts[0] = kS + tilebase; dsts[1] = qS + tilebase; dsts[2] = vS + tilebase;

  #pragma unroll
  for (int m = 0; m < 3; m++) {
    float vals[4][4];
    #pragma unroll
    for (int g = 0; g < 4; g++) {
      f32x4_t acc = {0.f, 0.f, 0.f, 0.f};
      #pragma unroll
      for (int kh = 0; kh < 2; kh++) {
        bf16x8_t wf = ld16(&Wl[m][g * 16 + l15][kh * 32 + quad * 8]);
        acc = mfma16(xf[kh], wf, acc);
      }
      #pragma unroll
      for (int r = 0; r < 4; r++)
        vals[g][r] = (m == 1) ? acc[r] * QSCALE : acc[r];
    }
    #pragma unroll
    for (int g = 0; g < 4; g++)
      #pragma unroll
      for (int r = 0; r < 4; r++)
        ylds[w * 16 + quad * 4 + r][g * 16 + l15] = f2bf(vals[g][r]);
    __syncthreads();
    if (m < 2) {
      #pragma unroll
      for (int kk = 0; kk < 2; kk++) {
        bf16x8_t f = ld16(&ylds[w * 16 + l15][kk * 32 + quad * 8]);
        *(int4*)(dsts[m] + (w * 2 + kk) * 512 + lane * 8) = __builtin_bit_cast(int4, f);
      }
    } else {
      #pragma unroll
      for (int kk = 0; kk < 2; kk++) {
        u16 tmp[8];
        #pragma unroll
        for (int j = 0; j < 8; j++)
          tmp[j] = ylds[kk * 32 + quad * 8 + j][w * 16 + l15];
        *(int4*)(dsts[2] + (kk * 4 + w) * 512 + lane * 8) = *(const int4*)tmp;
      }
    }
    __syncthreads();
  }
}

// ---------------- flash v13: 64 q-rows per wave (K/V traffic halved: 266 -> 133 MB) ----------------
// 256 blocks x 8 waves. Block (b, pair p, kv-half h): processes q64-tiles i1=p, i2=63-p, each over
// its kv chunk [lo,hi) (chunk split (nk+1)/2). Per-block visits 32-33, per-wave <=5 (uniform grid).
// v12 A/B pipeline kept: A(ph)->pT slice par^1 while B(ph-1) consumes slice par.
// Per-tile in-LDS 8-wave merge -> UNNORMALIZED partial (O 16KB, L 256B) per (tile, h); tiny
// HeadV1_out kernel sums the 2 halves and normalizes (8 MB partial traffic total).
__global__ __launch_bounds__(512, 2) void HeadV1_flash(
    const u16* __restrict__ qS, const u16* __restrict__ kS,
    const u16* __restrict__ vS, float* __restrict__ Opart,
    float* __restrict__ Lpart)
{
  __shared__ __align__(16) char smem[81920];
  u16  (*pT)[2][64][36] = (u16 (*)[2][64][36])smem;             // [8][2][64][36] u16 = 73728 B (main loop)
  float (*chk)[16][66]  = (float (*)[16][66])smem;              // [8][16][66] f32 = 33792 B (overlays pT)
  float (*stg)[68]      = (float (*)[68])(smem + 33792);        // [64][68] f32 = 17408 B (overlays pT)
  float (*lst)[4][64]   = (float (*)[4][64])(smem + 73728);     // [8][4][64] f32 = 8192 B (outside pT)

  const int t    = threadIdx.x;
  const int w    = t >> 6;        // 0..7
  const int lane = t & 63;
  const int l15  = lane & 15;
  const int quad = lane >> 4;

  const int b = blockIdx.x & 3;
  const int s = blockIdx.x >> 2;       // 0..63
  const int p = s >> 1;                // pair 0..31
  const int h = s & 1;                 // kv-half chunk

  const f32x4_t zero4 = {0.f, 0.f, 0.f, 0.f};
  const u16* kb = kS + ((long)(b * 64)) * 4096 + lane * 8;
  const u16* vb = vS + ((long)(b * 64)) * 4096 + lane * 8;

  #pragma unroll 1
  for (int tau = 0; tau < 2; tau++) {
    const int i   = tau ? (63 - p) : p;  // q64-tile index
    const int nk  = i + 1;               // kv tiles needed (last one masked)
    const int mid = (nk + 1) >> 1;
    const int lo  = h ? mid : 0;
    const int hi  = h ? nk : mid;
    const int qr0 = i * 64;

    bf16x8_t qfrag[4][2];
    {
      const u16* qtile = qS + ((long)(b * 64 + i)) * 4096 + lane * 8;
      #pragma unroll
      for (int ct = 0; ct < 4; ct++)
        #pragma unroll
        for (int kd = 0; kd < 2; kd++)
          qfrag[ct][kd] = ld16(qtile + (ct * 2 + kd) * 512);
    }

    f32x4_t O[4][4];   // [dt][ct]
    #pragma unroll
    for (int a = 0; a < 4; a++)
      #pragma unroll
      for (int c = 0; c < 4; c++)
        O[a][c] = zero4;
    float Lp[4] = {0.f, 0.f, 0.f, 0.f};

    // stage A: QK MFMA + mask + exp2 + truncate-pack -> pT[w][par_]; accumulates Lp
    auto Astage = [&](int kt_, int kk_, int par_, const bf16x8_t* kf) {
      const bool ismask = (kt_ == nk - 1);
      const int kv0 = kt_ * 64;
      #pragma unroll
      for (int rtl = 0; rtl < 2; rtl++) {
        const int rt = kk_ * 2 + rtl;
        #pragma unroll
        for (int ct = 0; ct < 4; ct++) {
          f32x4_t acc = zero4;
          acc = mfma16(kf[2 * rtl + 0], qfrag[ct][0], acc);
          acc = mfma16(kf[2 * rtl + 1], qfrag[ct][1], acc);
          if (ismask) {
            const int kvl = kv0 + rt * 16 + quad * 4;
            const int qi  = qr0 + ct * 16 + l15;
            #pragma unroll
            for (int r = 0; r < 4; r++)
              if (kvl + r > qi) acc[r] = -1e30f;   // v_exp -> 0
          }
          const float p0 = __builtin_amdgcn_exp2f(acc[0]);
          const float p1 = __builtin_amdgcn_exp2f(acc[1]);
          const float p2 = __builtin_amdgcn_exp2f(acc[2]);
          const float p3 = __builtin_amdgcn_exp2f(acc[3]);
          const u32 u0 = __builtin_bit_cast(u32, p0);
          const u32 u1 = __builtin_bit_cast(u32, p1);
          const u32 u2 = __builtin_bit_cast(u32, p2);
          const u32 u3 = __builtin_bit_cast(u32, p3);
          const u32 h1 = u1 & 0xFFFF0000u, h3 = u3 & 0xFFFF0000u;
          // L sums EXACTLY the truncated values PV consumes
          const float q0 = __builtin_bit_cast(float, u0 & 0xFFFF0000u);
          const float q1 = __builtin_bit_cast(float, h1);
          const float q2 = __builtin_bit_cast(float, u2 & 0xFFFF0000u);
          const float q3 = __builtin_bit_cast(float, h3);
          Lp[ct] += (q0 + q1) + (q2 + q3);
          uint2 pk;
          pk.x = (u0 >> 16) | h1;
          pk.y = (u2 >> 16) | h3;
          *(uint2*)&pT[w][par_][ct * 16 + l15][rtl * 16 + quad * 4] = pk;
        }
      }
    };

    // stage B: read pf from slice, PV MFMA
    auto Bstage = [&](int par_, const bf16x8_t* vf) {
      bf16x8_t pf[4];
      #pragma unroll
      for (int ct = 0; ct < 4; ct++)
        pf[ct] = ld16(&pT[w][par_][ct * 16 + l15][quad * 8]);
      __builtin_amdgcn_s_setprio(1);
      #pragma unroll
      for (int dt = 0; dt < 4; dt++)
        #pragma unroll
        for (int ct = 0; ct < 4; ct++)
          O[dt][ct] = mfma16(vf[dt], pf[ct], O[dt][ct]);
      __builtin_amdgcn_s_setprio(0);
    };

    const int span = hi - lo;
    const int nv = (w < span) ? ((span - 1 - w) / 8 + 1) : 0;

    if (nv > 0) {
      bf16x8_t vfC[4];
      int par = 0;
      { // prologue: phase 0 = (kt=lo+w, kk=0)
        const u16* kt_ = kb + (long)(lo + w) * 4096;
        const u16* vt_ = vb + (long)(lo + w) * 4096;
        bf16x8_t kfT[4];
        #pragma unroll
        for (int f = 0; f < 4; f++) { kfT[f] = ld16(kt_ + f * 512); vfC[f] = ld16(vt_ + f * 512); }
        Astage(lo + w, 0, 0, kfT);
      }
      const int nph = 2 * nv;
      for (int ph = 1; ph < nph; ph++) {
        const int ktP = lo + w + (ph >> 1) * 8;
        const int kkP = ph & 1;
        const u16* kt_ = kb + (long)ktP * 4096 + kkP * 2048;
        const u16* vt_ = vb + (long)ktP * 4096 + kkP * 2048;
        bf16x8_t kfT[4], vfN[4];
        #pragma unroll
        for (int f = 0; f < 4; f++) { kfT[f] = ld16(kt_ + f * 512); vfN[f] = ld16(vt_ + f * 512); }
        Bstage(par, vfC);               // consume phase ph-1; covers kfT/vfN latency
        Astage(ktP, kkP, par ^ 1, kfT); // produce phase ph into the other slice
        #pragma unroll
        for (int f = 0; f < 4; f++) vfC[f] = vfN[f];
        par ^= 1;
      }
      Bstage(par, vfC);                 // epilogue
    }

    // ---- 8-wave in-LDS merge for this tile ----
    #pragma unroll
    for (int ct = 0; ct < 4; ct++)
      lst[w][quad][ct * 16 + l15] = Lp[ct];
    __syncthreads();  // all waves done with pT; chk/stg overlay it

    #pragma unroll
    for (int dt = 0; dt < 4; dt++) {
      #pragma unroll
      for (int ct = 0; ct < 4; ct++)
        #pragma unroll
        for (int r = 0; r < 4; r++)
          chk[w][quad * 4 + r][ct * 16 + l15] = O[dt][ct][r];
      __syncthreads();
      #pragma unroll
      for (int rep = 0; rep < 2; rep++) {
        const int cell = rep * 512 + t;          // 1024 = 16 d x 64 q
        const int d2 = cell >> 6, q = cell & 63;
        float sacc = 0.f;
        #pragma unroll
        for (int w2 = 0; w2 < 8; w2++) sacc += chk[w2][d2][q];
        stg[q][dt * 16 + d2] = sacc;
      }
      __syncthreads();
    }

    { // dump UNNORMALIZED partial (coalesced float4) + L
      float* Od = Opart + ((long)(b * 64 + i)) * 8192 + (long)h * 4096;
      #pragma unroll
      for (int rep = 0; rep < 2; rep++) {
        const int idx = rep * 512 + t;           // 1024 float4 = 64 q x 16
        const int q = idx >> 4, dg = idx & 15;
        *(f32x4_t*)(Od + q * 64 + dg * 4) = *(const f32x4_t*)&stg[q][dg * 4];
      }
      if (t < 64) {
        float L = 0.f;
        #pragma unroll
        for (int w2 = 0; w2 < 8; w2++)
          #pragma unroll
          for (int qd = 0; qd < 4; qd++) L += lst[w2][qd][t];
        Lpart[((long)(b * 64 + i)) * 128 + h * 64 + t] = L;
      }
    }
    __syncthreads();  // before next tile reuses pT/lst
  }
}

// ---------------- out: sum 2 kv-half partials per q64-tile, normalize, write ----------------
__global__ __launch_bounds__(256) void HeadV1_out(
    const float* __restrict__ Opart, const float* __restrict__ Lpart,
    float* __restrict__ outg)
{
  __shared__ float Ls[64];
  const int t = threadIdx.x;
  const int tile = blockIdx.x;          // b*64 + i
  const int b = tile >> 6, i = tile & 63;
  const float* O0 = Opart + (long)tile * 8192;
  const float* O1 = O0 + 4096;
  if (t < 64) Ls[t] = Lpart[(long)tile * 128 + t] + Lpart[(long)tile * 128 + 64 + t];
  __syncthreads();
  #pragma unroll
  for (int r = 0; r < 4; r++) {
    const int idx = r * 256 + t;        // 1024 float4 = 64 q x 16
    const int q = idx >> 4, c4 = idx & 15;
    f32x4_t v = *(const f32x4_t*)(O0 + q * 64 + c4 * 4);
    v += *(const f32x4_t*)(O1 + q * 64 + c4 * 4);
    const float invL = 1.0f / Ls[q];
    v *= invL;
    *(f32x4_t*)(outg + ((long)b * Tt + (long)(i * 64 + q)) * 64 + c4 * 4) = v;
  }
}

extern "C" void kernel_launch(void* const* d_in, const int* in_sizes, int n_in,
                              void* d_out, int out_size, void* d_ws, size_t ws_size,
                              hipStream_t stream) {
  (void)in_sizes; (void)n_in; (void)out_size; (void)ws_size;
  const float* x  = (const float*)d_in[0];
  const float* Wk = (const float*)d_in[1];
  const float* Wq = (const float*)d_in[2];
  const float* Wv = (const float*)d_in[3];
  float* out = (float*)d_out;
  // workspace: qS 2MB | kS 2MB | vS 2MB (fragment order) | Opart 8MB | Lpart 128KB
  u16* qw = (u16*)d_ws;
  u16* kw = qw + (size_t)Bb * Tt * Dd;
  u16* vw = kw + (size_t)Bb * Tt * Dd;
  float* Op = (float*)(vw + (size_t)Bb * Tt * Dd);
  float* Lp = Op + (size_t)(Bb * 64) * 8192;

  HeadV1_proj<<<(Bb * Tt) / 64, 256, 0, stream>>>(x, Wk, Wq, Wv, qw, kw, vw);
  HeadV1_flash<<<256, 512, 0, stream>>>(qw, kw, vw, Op, Lp);
  HeadV1_out<<<Bb * 64, 256, 0, stream>>>(Op, Lp, out);
}